// Round 2
// baseline (317.373 us; speedup 1.0000x reference)
//
#include <hip/hip_runtime.h>
#include <hip/hip_bf16.h>
#include <stdint.h>

// ---------------------------------------------------------------------------
// TripletAggregateUngated: B=2, N=256, W=128, H=8, D=16
//  K0: weight prep (bf16 Wcat[n][k], WOt[w][c'])
//  K1: LN + proj GEMM (B-frags direct from L2); V_in stored direct from acc
//      (8-B runs); V_out via 17 KB LDS transpose. LDS 17.4 KB -> ~3 blocks/CU.
//  K2: dual softmax over k; bf16 [b][h][i][k] outputs.
//  K3: einsum batched GEMMs, BK=128 x2, 64 KB LDS, VaP2 [ph][m][16] output.
//  K4: Va @ W_O: A staged per-ph slab (32 KB), B direct from L2.
// ---------------------------------------------------------------------------

typedef short short8 __attribute__((ext_vector_type(8)));
typedef short short4v __attribute__((ext_vector_type(4)));
typedef float floatx4 __attribute__((ext_vector_type(4)));

#define AS1(p) ((const __attribute__((address_space(1))) void*)(p))
#define AS3(p) ((__attribute__((address_space(3))) void*)(p))

__device__ inline short f2bf(float v) {
    __hip_bfloat16 h = __float2bfloat16(v);
    short s;
    __builtin_memcpy(&s, &h, 2);
    return s;
}

// ---------------------------------------------------------------------------
// K0: Wcat[n][k] (n<256: W_V[k][n]; else W_E[k][n-256]); WOt[w][c'] with
// c' = ph*16+d  ->  W_O row (c'&15)*16 + (c'>>4).
// ---------------------------------------------------------------------------
__global__ __launch_bounds__(128) void k0_prep(const float* __restrict__ WV,
                                               const float* __restrict__ WE,
                                               const float* __restrict__ WO,
                                               short* __restrict__ Wcat,
                                               short* __restrict__ WOt) {
    int bx = blockIdx.x;
    if (bx < 272) {
        int n = bx, k = threadIdx.x;
        float v = (n < 256) ? WV[k * 256 + n] : WE[k * 16 + (n - 256)];
        Wcat[n * 128 + k] = f2bf(v);
    } else {
        int w = bx - 272;
        for (int it = 0; it < 2; ++it) {
            int c = threadIdx.x + it * 128;
            float v = WO[((c & 15) * 16 + (c >> 4)) * 128 + w];
            WOt[w * 256 + c] = f2bf(v);
        }
    }
}

// ---------------------------------------------------------------------------
// K1: per 8x8 edge patch. LDS = one 64x136 buffer (As for LN->frags, then
// CsO for the V_out transpose). B-fragments read straight from Wcat (L2).
// ---------------------------------------------------------------------------
__global__ __launch_bounds__(256) void k1_ln_proj(
    const float* __restrict__ e, const float* __restrict__ ln_g,
    const float* __restrict__ ln_b, const float* __restrict__ b_V,
    const float* __restrict__ b_E, const short* __restrict__ Wcat,
    short* __restrict__ VinT, short* __restrict__ VoutT,
    float* __restrict__ Ef) {
    __shared__ short Buf[64][136];  // 17408 B; As then CsO (cols 0..127)

    const int tid = threadIdx.x;
    const int lane = tid & 63;
    const int w = tid >> 6;
    const int bx = blockIdx.x;
    const int b = bx >> 10;
    const int rem = bx & 1023;
    const int r1_0 = (rem >> 5) << 3;
    const int r2_0 = (rem & 31) << 3;

    // LayerNorm: 4 threads per edge row, 32 f32 each (rows stay wave-local)
    {
        int row = tid >> 2, seg = tid & 3;
        int r1l = row >> 3, r2l = row & 7;
        const float* ep = e + (((size_t)b * 256 + (r1_0 + r1l)) * 256 +
                               (r2_0 + r2l)) * 128 + seg * 32;
        float v[32];
        float s = 0.f, s2 = 0.f;
#pragma unroll
        for (int i = 0; i < 8; ++i) {
            float4 t = ((const float4*)ep)[i];
            v[4 * i] = t.x; v[4 * i + 1] = t.y; v[4 * i + 2] = t.z; v[4 * i + 3] = t.w;
            s += t.x + t.y + t.z + t.w;
            s2 += t.x * t.x + t.y * t.y + t.z * t.z + t.w * t.w;
        }
        s += __shfl_xor(s, 1); s2 += __shfl_xor(s2, 1);
        s += __shfl_xor(s, 2); s2 += __shfl_xor(s2, 2);
        float mean = s * 0.0078125f;
        float var = s2 * 0.0078125f - mean * mean;
        float rs = rsqrtf(var + 1e-5f);
#pragma unroll
        for (int i = 0; i < 8; ++i) {
            float4 gg = ((const float4*)(ln_g + seg * 32))[i];
            float4 bb = ((const float4*)(ln_b + seg * 32))[i];
            Buf[row][seg * 32 + 4 * i + 0] = f2bf((v[4 * i + 0] - mean) * rs * gg.x + bb.x);
            Buf[row][seg * 32 + 4 * i + 1] = f2bf((v[4 * i + 1] - mean) * rs * gg.y + bb.y);
            Buf[row][seg * 32 + 4 * i + 2] = f2bf((v[4 * i + 2] - mean) * rs * gg.z + bb.z);
            Buf[row][seg * 32 + 4 * i + 3] = f2bf((v[4 * i + 3] - mean) * rs * gg.w + bb.w);
        }
    }
    __syncthreads();

    // GEMM: wave w owns edges [w*16, w*16+16); 17 n-subtiles; K=128.
    const int ln_ = lane & 15, quad = lane >> 4;
    const int m0 = w * 16;
    short8 af[4];
#pragma unroll
    for (int kk = 0; kk < 4; ++kk)
        af[kk] = *(const short8*)&Buf[m0 + ln_][kk * 32 + quad * 8];
    floatx4 acc[17] = {};
#pragma unroll
    for (int kk = 0; kk < 4; ++kk) {
        const short* wp = Wcat + (kk * 4 + quad) * 8 + ln_ * 128;
#pragma unroll
        for (int nt = 0; nt < 17; ++nt) {
            short8 bq = *(const short8*)(wp + nt * 2048);
            acc[nt] = __builtin_amdgcn_mfma_f32_16x16x32_bf16(af[kk], bq, acc[nt], 0, 0, 0);
        }
    }

    // Epilogue. Lane rows: edge = m0 + quad*4 + r -> r1l = w*2+(quad>>1),
    // r2l = (quad&1)*4 + r (4 consecutive).
    const int r1l = w * 2 + (quad >> 1);
    const int r2b = (quad & 1) * 4;
#pragma unroll
    for (int nt = 0; nt < 17; ++nt) {
        int c = nt * 16 + ln_;
        if (nt < 8) {
            // V_in: direct 8-B store, run over r2
            float bias = b_V[c];
            int d = c >> 3, hh = c & 7;
            short4v vals;
#pragma unroll
            for (int r = 0; r < 4; ++r) vals[r] = f2bf(acc[nt][r] + bias);
            size_t off = (((size_t)(b * 8 + hh) * 256 + (r1_0 + r1l)) * 16 + d) * 256 +
                         r2_0 + r2b;
            *(short4v*)(VinT + off) = vals;
        } else if (nt < 16) {
            // V_out: stage to LDS for transpose (wave-local rows)
            float bias = b_V[c];
            int cc = c - 128;
#pragma unroll
            for (int r = 0; r < 4; ++r)
                Buf[m0 + quad * 4 + r][cc] = f2bf(acc[nt][r] + bias);
        } else {
            float bias = b_E[ln_];
#pragma unroll
            for (int r = 0; r < 4; ++r) {
                int edge = m0 + quad * 4 + r;
                Ef[(((size_t)b * 256 + (r1_0 + (edge >> 3))) * 256 +
                    (r2_0 + (edge & 7))) * 16 + ln_] = acc[nt][r] + bias;
            }
        }
    }
    __syncthreads();

    // V_out scatter: 16-B runs over r1. tid -> (d, hh, rl2)
    {
        int d = tid & 15;
        int hh = (tid >> 4) & 7;
        int rl2 = tid >> 7;
        int cc = d * 8 + hh;
#pragma unroll
        for (int rr = 0; rr < 4; ++rr) {
            int rl = rl2 * 4 + rr;
            short8 vals;
#pragma unroll
            for (int q = 0; q < 8; ++q) vals[q] = Buf[q * 8 + rl][cc];
            size_t off = (((size_t)(b * 8 + hh) * 256 + (r2_0 + rl)) * 16 + d) * 256 + r1_0;
            *(short8*)(VoutT + off) = vals;
        }
    }
}

// ---------------------------------------------------------------------------
// K2: softmaxes. Block = (b,i). Outputs bf16 [b][h][i][k].
// ---------------------------------------------------------------------------
__global__ __launch_bounds__(256) void k2_softmax(const float* __restrict__ Ef,
                                                  const float* __restrict__ mask,
                                                  short* __restrict__ Ain,
                                                  short* __restrict__ AoutT) {
    __shared__ float red[4][16];
    int bi = blockIdx.x;
    int b = bi >> 8, i = bi & 255;
    int k = threadIdx.x;
    int wid = k >> 6, lane = k & 63;

    float v[16];
    {
        const float4* pin = (const float4*)(Ef + (((size_t)b * 256 + i) * 256 + k) * 16);
        float4 a0 = pin[0], a1 = pin[1];
        float mi = mask[((size_t)b * 256 + i) * 256 + k];
        v[0] = a0.x + mi; v[1] = a0.y + mi; v[2] = a0.z + mi; v[3] = a0.w + mi;
        v[4] = a1.x + mi; v[5] = a1.y + mi; v[6] = a1.z + mi; v[7] = a1.w + mi;
        const float4* po = (const float4*)(Ef + (((size_t)b * 256 + k) * 256 + i) * 16 + 8);
        float4 c0 = po[0], c1 = po[1];
        float mo = mask[((size_t)b * 256 + k) * 256 + i];
        v[8] = c0.x + mo; v[9] = c0.y + mo; v[10] = c0.z + mo; v[11] = c0.w + mo;
        v[12] = c1.x + mo; v[13] = c1.y + mo; v[14] = c1.z + mo; v[15] = c1.w + mo;
    }
    float wm[16];
#pragma unroll
    for (int ch = 0; ch < 16; ++ch) {
        float m = v[ch];
#pragma unroll
        for (int off = 1; off < 64; off <<= 1) m = fmaxf(m, __shfl_xor(m, off));
        wm[ch] = m;
    }
    if (lane == 0) {
#pragma unroll
        for (int ch = 0; ch < 16; ++ch) red[wid][ch] = wm[ch];
    }
    __syncthreads();
    float bmax[16];
#pragma unroll
    for (int ch = 0; ch < 16; ++ch)
        bmax[ch] = fmaxf(fmaxf(red[0][ch], red[1][ch]), fmaxf(red[2][ch], red[3][ch]));
    __syncthreads();
    float p[16], ws[16];
#pragma unroll
    for (int ch = 0; ch < 16; ++ch) {
        p[ch] = __expf(v[ch] - bmax[ch]);
        float s = p[ch];
#pragma unroll
        for (int off = 1; off < 64; off <<= 1) s += __shfl_xor(s, off);
        ws[ch] = s;
    }
    if (lane == 0) {
#pragma unroll
        for (int ch = 0; ch < 16; ++ch) red[wid][ch] = ws[ch];
    }
    __syncthreads();
#pragma unroll
    for (int ch = 0; ch < 8; ++ch) {
        float inv = 1.f / (red[0][ch] + red[1][ch] + red[2][ch] + red[3][ch]);
        Ain[(((size_t)b * 8 + ch) * 256 + i) * 256 + k] = f2bf(p[ch] * inv);
    }
#pragma unroll
    for (int ch = 8; ch < 16; ++ch) {
        float inv = 1.f / (red[0][ch] + red[1][ch] + red[2][ch] + red[3][ch]);
        AoutT[(((size_t)b * 8 + (ch - 8)) * 256 + i) * 256 + k] = f2bf(p[ch] * inv);
    }
}

// ---------------------------------------------------------------------------
// K3: per (b,h,part): C[i,jd] = sum_k A[i,k] V[jd,k]. 128x128 tile, BK=128 x2.
// LDS 64 KB (A chunks [0,2048), B [2048,4096)). Output VaP2[ph][m][16d].
// grid(x=i-tile 2, y=jd-tile 32, z=32): adjacent x share the B-tile (L2).
// ---------------------------------------------------------------------------
__global__ __launch_bounds__(256) void k3_einsum(const short* __restrict__ Ain,
                                                 const short* __restrict__ AoutT,
                                                 const short* __restrict__ VinT,
                                                 const short* __restrict__ VoutT,
                                                 short* __restrict__ VaP2) {
    __shared__ short AB[4096 * 8];  // 64 KB
    const int tid = threadIdx.x, lane = tid & 63, w = tid >> 6;
    const int i0 = blockIdx.x * 128;
    const int jd0 = blockIdx.y * 128;
    const int z = blockIdx.z;
    const int b = z >> 4, part = (z >> 3) & 1, h = z & 7;

    const short* Abase = (part ? AoutT : Ain) + ((size_t)(b * 8 + h)) * 65536 + (size_t)i0 * 256;
    const short* Bbase = (part ? VoutT : VinT) + ((size_t)(b * 8 + h)) * 1048576 + (size_t)jd0 * 256;

    const int ln_ = lane & 15, quad = lane >> 4;
    const int m0 = (w >> 1) * 64, n0 = (w & 1) * 64;
    floatx4 acc[4][4] = {};

    for (int kt = 0; kt < 2; ++kt) {
        if (kt) __syncthreads();
        for (int it = 0; it < 16; ++it) {
            int cid = w * 1024 + it * 64 + lane;
            int isB = cid >> 11;
            int lc = cid & 2047;
            int r = lc >> 4;
            int ck = (lc & 15) ^ (r & 15);
            const short* g = (isB ? Bbase : Abase) + r * 256 + kt * 128 + ck * 8;
            __builtin_amdgcn_global_load_lds(AS1(g), AS3(&AB[cid * 8]), 16, 0, 0);
        }
        __syncthreads();

        for (int kk = 0; kk < 4; ++kk) {
            int ckb = kk * 4 + quad;
            short8 aq[4], bq[4];
#pragma unroll
            for (int t = 0; t < 4; ++t) {
                int r = m0 + t * 16 + ln_;
                aq[t] = *(const short8*)&AB[(r * 16 + (ckb ^ (r & 15))) * 8];
            }
#pragma unroll
            for (int t = 0; t < 4; ++t) {
                int r = n0 + t * 16 + ln_;
                bq[t] = *(const short8*)&AB[(2048 + r * 16 + (ckb ^ (r & 15))) * 8];
            }
#pragma unroll
            for (int mt = 0; mt < 4; ++mt)
#pragma unroll
                for (int nt = 0; nt < 4; ++nt)
                    acc[mt][nt] = __builtin_amdgcn_mfma_f32_16x16x32_bf16(aq[mt], bq[nt], acc[mt][nt], 0, 0, 0);
        }
    }

    const int ph = part * 8 + h;
#pragma unroll
    for (int mt = 0; mt < 4; ++mt) {
#pragma unroll
        for (int nt = 0; nt < 4; ++nt) {
            int j = (jd0 + n0 + nt * 16) >> 4;
#pragma unroll
            for (int r = 0; r < 4; ++r) {
                int i = i0 + m0 + mt * 16 + quad * 4 + r;
                size_t m = ((size_t)b * 256 + i) * 256 + j;
                VaP2[((size_t)ph * 131072 + m) * 16 + ln_] = f2bf(acc[mt][nt][r]);
            }
        }
    }
}

// ---------------------------------------------------------------------------
// K4: out[m][w] = sum_c VaP2-gathered A[m][c] * WOt[w][c] + bO[w].
// A staged per-ph slab: LDS [p 8][half 2][m 128][8] = 32 KB, 2 K-iters.
// B-fragments direct from WOt (64 KB, L2-resident).
// ---------------------------------------------------------------------------
__global__ __launch_bounds__(256) void k4_proj(const short* __restrict__ VaP2,
                                               const short* __restrict__ WOt,
                                               const float* __restrict__ bO,
                                               float* __restrict__ out) {
    __shared__ short A_s[16384];  // 32 KB
    const int tid = threadIdx.x, lane = tid & 63, w = tid >> 6;
    const size_t m0g = (size_t)blockIdx.x * 128;
    const int ln_ = lane & 15, quad = lane >> 4;
    const int m0 = (w >> 1) * 64, n0 = (w & 1) * 64;
    floatx4 acc[4][4] = {};

    for (int kt = 0; kt < 2; ++kt) {
        if (kt) __syncthreads();
        for (int it = 0; it < 8; ++it) {
            int cid = w * 512 + it * 64 + lane;     // 0..2047
            int p = cid >> 8, rm = cid & 255, half = rm >> 7, m = rm & 127;
            const short* g = VaP2 + ((size_t)(kt * 8 + p) * 131072 + m0g + m) * 16 + half * 8;
            __builtin_amdgcn_global_load_lds(AS1(g), AS3(&A_s[cid * 8]), 16, 0, 0);
        }
        __syncthreads();

        for (int kk = 0; kk < 4; ++kk) {
            int ckb = kk * 4 + quad;
            int p = ckb >> 1, hf = ckb & 1;
            short8 aq[4], bq[4];
#pragma unroll
            for (int t = 0; t < 4; ++t) {
                int m = m0 + t * 16 + ln_;
                aq[t] = *(const short8*)&A_s[p * 2048 + hf * 1024 + m * 8];
            }
#pragma unroll
            for (int t = 0; t < 4; ++t) {
                int wr = n0 + t * 16 + ln_;
                bq[t] = *(const short8*)(WOt + wr * 256 + kt * 128 + ckb * 8);
            }
#pragma unroll
            for (int mt = 0; mt < 4; ++mt)
#pragma unroll
                for (int nt = 0; nt < 4; ++nt)
                    acc[mt][nt] = __builtin_amdgcn_mfma_f32_16x16x32_bf16(aq[mt], bq[nt], acc[mt][nt], 0, 0, 0);
        }
    }

#pragma unroll
    for (int nt = 0; nt < 4; ++nt) {
        int ww = n0 + nt * 16 + ln_;
        float bo = bO[ww];
#pragma unroll
        for (int mt = 0; mt < 4; ++mt) {
            size_t mb = m0g + m0 + mt * 16 + quad * 4;
#pragma unroll
            for (int r = 0; r < 4; ++r)
                out[(mb + r) * 128 + ww] = acc[mt][nt][r] + bo;
        }
    }
}

// ---------------------------------------------------------------------------
extern "C" void kernel_launch(void* const* d_in, const int* in_sizes, int n_in,
                              void* d_out, int out_size, void* d_ws, size_t ws_size,
                              hipStream_t stream) {
    (void)in_sizes; (void)n_in; (void)out_size; (void)ws_size;
    const float* e    = (const float*)d_in[0];
    const float* mask = (const float*)d_in[1];
    const float* ln_g = (const float*)d_in[2];
    const float* ln_b = (const float*)d_in[3];
    const float* W_V  = (const float*)d_in[4];
    const float* b_V  = (const float*)d_in[5];
    const float* W_E  = (const float*)d_in[6];
    const float* b_E  = (const float*)d_in[7];
    const float* W_O  = (const float*)d_in[8];
    const float* b_O  = (const float*)d_in[9];
    float* out = (float*)d_out;

    char* ws = (char*)d_ws;
    short* VinT  = (short*)(ws + 0);          //  33,554,432 B
    short* VoutT = (short*)(ws + 33554432);   //  33,554,432 B
    float* Ef    = (float*)(ws + 67108864);   //   8,388,608 B
    short* Ain   = (short*)(ws + 75497472);   //   2,097,152 B
    short* AoutT = (short*)(ws + 77594624);   //   2,097,152 B
    short* VaP2  = (short*)(ws + 79691776);   //  67,108,864 B
    short* Wcat  = (short*)(ws + 146800640);  //      69,632 B
    short* WOt   = (short*)(ws + 146870272);  //      65,536 B

    k0_prep<<<400, 128, 0, stream>>>(W_V, W_E, W_O, Wcat, WOt);
    k1_ln_proj<<<2048, 256, 0, stream>>>(e, ln_g, ln_b, b_V, b_E, Wcat, VinT, VoutT, Ef);
    k2_softmax<<<512, 256, 0, stream>>>(Ef, mask, Ain, AoutT);
    k3_einsum<<<dim3(2, 32, 32), 256, 0, stream>>>(Ain, AoutT, VinT, VoutT, VaP2);
    k4_proj<<<1024, 256, 0, stream>>>(VaP2, WOt, b_O, out);
}

// Round 3
// 245.757 us; speedup vs baseline: 1.2914x; 1.2914x over previous
//
#include <hip/hip_runtime.h>
#include <hip/hip_bf16.h>
#include <stdint.h>

// ---------------------------------------------------------------------------
// TripletAggregateUngated: B=2, N=256, W=128, H=8, D=16
//  K0: weight prep: Wcat2[2][144][128] bf16 (v=0: W_V[:, :128]|W_E[:, :8]|pad,
//      v=1: W_V[:,128:]|W_E[:,8:]|pad), bcat[2][144], WOt[w][c'] bf16.
//  K1: block = (b, fixed row, all 256 k). LN -> A-tile (LDS, XOR-swizzled) ->
//      GEMM vs Wcat2 -> V stored DIRECT from acc as contiguous 8-B runs
//      (full-line writes), E -> in-block softmax -> Ain/AoutT. K2 eliminated.
//  K3: einsum batched GEMMs (unchanged from round 2).
//  K4: Va @ W_O (unchanged from round 2).
// ---------------------------------------------------------------------------

typedef short short8 __attribute__((ext_vector_type(8)));
typedef short short4v __attribute__((ext_vector_type(4)));
typedef float floatx4 __attribute__((ext_vector_type(4)));

#define AS1(p) ((const __attribute__((address_space(1))) void*)(p))
#define AS3(p) ((__attribute__((address_space(3))) void*)(p))

__device__ inline short f2bf(float v) {
    uint32_t u = __builtin_bit_cast(uint32_t, v);
    u += 0x7FFFu + ((u >> 16) & 1u);   // RNE; inputs finite
    return (short)(u >> 16);
}

// ---------------------------------------------------------------------------
// K0: weight/bias prep.
// ---------------------------------------------------------------------------
__global__ __launch_bounds__(128) void k0_prep(const float* __restrict__ WV,
                                               const float* __restrict__ WE,
                                               const float* __restrict__ WO,
                                               short* __restrict__ Wcat2,
                                               short* __restrict__ WOt,
                                               const float* __restrict__ bV,
                                               const float* __restrict__ bE,
                                               float* __restrict__ bcat) {
    int bx = blockIdx.x;
    if (bx < 288) {
        int v = bx / 144, n = bx % 144, k = threadIdx.x;
        float val = 0.f;
        if (n < 128) val = WV[k * 256 + v * 128 + n];
        else if (n < 136) val = WE[k * 16 + v * 8 + (n - 128)];
        Wcat2[(v * 144 + n) * 128 + k] = f2bf(val);
    } else if (bx < 416) {
        int w = bx - 288;
        for (int it = 0; it < 2; ++it) {
            int c = threadIdx.x + it * 128;
            float val = WO[((c & 15) * 16 + (c >> 4)) * 128 + w];
            WOt[w * 256 + c] = f2bf(val);
        }
    } else {
        for (int it = 0; it < 3; ++it) {
            int idx = it * 128 + threadIdx.x;
            if (idx < 288) {
                int v = idx / 144, n = idx % 144;
                float val = 0.f;
                if (n < 128) val = bV[v * 128 + n];
                else if (n < 136) val = bE[v * 8 + (n - 128)];
                bcat[idx] = val;
            }
        }
    }
}

// ---------------------------------------------------------------------------
// K1: fused LN + projection + softmax.
// blockIdx: x = fixed row (256), y = b (2), z = variant v (2).
//  v=0: fix=i (r1), k=r2  -> V_in cols, E_in softmax (axis=2)
//  v=1: fix=j (r2), k=r1  -> V_out cols, E_out softmax (axis=1)
// A-tile: 256 rows x 128 cols bf16 in LDS, 16-B granule g stored at
// position g ^ (row & 15) within the row (conflict-spread, b128-aligned).
// ---------------------------------------------------------------------------
__global__ __launch_bounds__(256, 2) void k1_ln_proj(
    const float* __restrict__ e, const float* __restrict__ ln_g,
    const float* __restrict__ ln_b, const float* __restrict__ mask,
    const short* __restrict__ Wcat2, const float* __restrict__ bcat,
    short* __restrict__ VinT, short* __restrict__ VoutT,
    short* __restrict__ Ain, short* __restrict__ AoutT) {
    __shared__ short At[256 * 128];   // 64 KB
    __shared__ float maskb[256];
    __shared__ float redm[4][8];
    __shared__ float reds[4][8];

    const int tid = threadIdx.x;
    const int fix = blockIdx.x;
    const int b = blockIdx.y;
    const int v = blockIdx.z;
    const int estride = v ? 256 : 1;
    const size_t ebase = (size_t)b * 65536 + (size_t)fix * (v ? 1 : 256);
    const short* Wv = Wcat2 + v * 144 * 128;
    const float* bc = bcat + v * 144;
    short* Vdst = v ? VoutT : VinT;
    short* Adst = v ? AoutT : Ain;

    // mask row -> LDS
    maskb[tid] = mask[(size_t)b * 65536 + (v ? (size_t)tid * 256 + fix
                                             : (size_t)fix * 256 + tid)];

    // LayerNorm: 4 threads/row (coalesced 64-B groups), 4 passes over rows.
    {
        const int rq = tid & 3;       // 16-B column group within 64-B
        const int rowi = tid >> 2;    // 64 rows per pass
#pragma unroll
        for (int pass = 0; pass < 4; ++pass) {
            int row = pass * 64 + rowi;
            const float* ep = e + (ebase + (size_t)row * estride) * 128 + rq * 4;
            float4 val[8];
            float s = 0.f, s2 = 0.f;
#pragma unroll
            for (int i = 0; i < 8; ++i) {
                val[i] = *(const float4*)(ep + i * 16);
                s += val[i].x + val[i].y + val[i].z + val[i].w;
                s2 += val[i].x * val[i].x + val[i].y * val[i].y +
                      val[i].z * val[i].z + val[i].w * val[i].w;
            }
            s += __shfl_xor(s, 1); s2 += __shfl_xor(s2, 1);
            s += __shfl_xor(s, 2); s2 += __shfl_xor(s2, 2);
            float mean = s * 0.0078125f;
            float var = s2 * 0.0078125f - mean * mean;
            float rs = rsqrtf(var + 1e-5f);
#pragma unroll
            for (int i = 0; i < 8; ++i) {
                int col = i * 16 + rq * 4;
                float4 gg = *(const float4*)(ln_g + col);
                float4 bb = *(const float4*)(ln_b + col);
                short4v o;
                o[0] = f2bf((val[i].x - mean) * rs * gg.x + bb.x);
                o[1] = f2bf((val[i].y - mean) * rs * gg.y + bb.y);
                o[2] = f2bf((val[i].z - mean) * rs * gg.z + bb.z);
                o[3] = f2bf((val[i].w - mean) * rs * gg.w + bb.w);
                int g = col >> 3;                 // 16-B granule index 0..15
                int cp = g ^ (row & 15);
                int half = (col >> 2) & 1;
                *(short4v*)&At[row * 128 + cp * 8 + half * 4] = o;
            }
        }
    }
    __syncthreads();

    const int lane = tid & 63, w = tid >> 6;
    const int ln_ = lane & 15, quad = lane >> 4;
    // A-frag granule position for (kk): (kk*4+quad) ^ ln_  (row & 15 == ln_)
    // wave w owns k-rows w*64 .. w*64+63 (4 m-subtiles of 16).

    // ---- V chunks: cols [chunk*64, chunk*64+64) ----
#pragma unroll
    for (int chunk = 0; chunk < 2; ++chunk) {
        floatx4 acc[4][4] = {};   // [mt][ntl]
#pragma unroll
        for (int kk = 0; kk < 4; ++kk) {
            int cp = (kk * 4 + quad) ^ ln_;
            short8 aq[4];
#pragma unroll
            for (int mt = 0; mt < 4; ++mt) {
                int r = w * 64 + mt * 16 + ln_;
                aq[mt] = *(const short8*)&At[r * 128 + cp * 8];
            }
            short8 bq[4];
#pragma unroll
            for (int ntl = 0; ntl < 4; ++ntl) {
                int n = chunk * 64 + ntl * 16 + ln_;
                bq[ntl] = *(const short8*)(Wv + n * 128 + (kk * 4 + quad) * 8);
            }
#pragma unroll
            for (int mt = 0; mt < 4; ++mt)
#pragma unroll
                for (int ntl = 0; ntl < 4; ++ntl)
                    acc[mt][ntl] = __builtin_amdgcn_mfma_f32_16x16x32_bf16(
                        aq[mt], bq[ntl], acc[mt][ntl], 0, 0, 0);
        }
        // direct stores: lane owns col c, k-run quad*4..quad*4+3 (8 B)
#pragma unroll
        for (int ntl = 0; ntl < 4; ++ntl) {
            int c = chunk * 64 + ntl * 16 + ln_;
            float bias = bc[c];
            int d = c >> 3, hh = c & 7;
            size_t rowbase = (((size_t)(b * 8 + hh) * 256 + fix) * 16 + d) * 256;
#pragma unroll
            for (int mt = 0; mt < 4; ++mt) {
                short4v o;
#pragma unroll
                for (int r = 0; r < 4; ++r) o[r] = f2bf(acc[mt][ntl][r] + bias);
                *(short4v*)(Vdst + rowbase + w * 64 + mt * 16 + quad * 4) = o;
            }
        }
    }

    // ---- E chunk: cols 128..143 (8 real + 8 pad) + softmax over k ----
    {
        floatx4 accE[4] = {};
        int n = 128 + ln_;
#pragma unroll
        for (int kk = 0; kk < 4; ++kk) {
            int cp = (kk * 4 + quad) ^ ln_;
            short8 bq = *(const short8*)(Wv + n * 128 + (kk * 4 + quad) * 8);
#pragma unroll
            for (int mt = 0; mt < 4; ++mt) {
                int r = w * 64 + mt * 16 + ln_;
                short8 aq = *(const short8*)&At[r * 128 + cp * 8];
                accE[mt] = __builtin_amdgcn_mfma_f32_16x16x32_bf16(
                    aq, bq, accE[mt], 0, 0, 0);
            }
        }
        float bias = bc[128 + ln_];
        float vE[16];
        float m = -3.4e38f;
#pragma unroll
        for (int mt = 0; mt < 4; ++mt)
#pragma unroll
            for (int r = 0; r < 4; ++r) {
                int k = w * 64 + mt * 16 + quad * 4 + r;
                float x = accE[mt][r] + bias + maskb[k];
                vE[mt * 4 + r] = x;
                m = fmaxf(m, x);
            }
        m = fmaxf(m, __shfl_xor(m, 16));
        m = fmaxf(m, __shfl_xor(m, 32));
        if (quad == 0 && ln_ < 8) redm[w][ln_] = m;
        __syncthreads();
        int hs = ln_ & 7;
        float bmax = fmaxf(fmaxf(redm[0][hs], redm[1][hs]),
                           fmaxf(redm[2][hs], redm[3][hs]));
        float p[16], s = 0.f;
#pragma unroll
        for (int i = 0; i < 16; ++i) { p[i] = __expf(vE[i] - bmax); s += p[i]; }
        s += __shfl_xor(s, 16);
        s += __shfl_xor(s, 32);
        if (quad == 0 && ln_ < 8) reds[w][ln_] = s;
        __syncthreads();
        float inv = 1.f / (reds[0][hs] + reds[1][hs] + reds[2][hs] + reds[3][hs]);
        if (ln_ < 8) {
            size_t rowbase = (size_t)(b * 8 + ln_) * 65536 + (size_t)fix * 256;
#pragma unroll
            for (int mt = 0; mt < 4; ++mt) {
                short4v o;
#pragma unroll
                for (int r = 0; r < 4; ++r) o[r] = f2bf(p[mt * 4 + r] * inv);
                *(short4v*)(Adst + rowbase + w * 64 + mt * 16 + quad * 4) = o;
            }
        }
    }
}

// ---------------------------------------------------------------------------
// K3: per (b,h,part): C[i,jd] = sum_k A[i,k] V[jd,k]. 128x128 tile, BK=128 x2.
// LDS 64 KB. Output VaP2[ph][m][16d] bf16.
// ---------------------------------------------------------------------------
__global__ __launch_bounds__(256) void k3_einsum(const short* __restrict__ Ain,
                                                 const short* __restrict__ AoutT,
                                                 const short* __restrict__ VinT,
                                                 const short* __restrict__ VoutT,
                                                 short* __restrict__ VaP2) {
    __shared__ short AB[4096 * 8];  // 64 KB
    const int tid = threadIdx.x, lane = tid & 63, w = tid >> 6;
    const int i0 = blockIdx.x * 128;
    const int jd0 = blockIdx.y * 128;
    const int z = blockIdx.z;
    const int b = z >> 4, part = (z >> 3) & 1, h = z & 7;

    const short* Abase = (part ? AoutT : Ain) + ((size_t)(b * 8 + h)) * 65536 + (size_t)i0 * 256;
    const short* Bbase = (part ? VoutT : VinT) + ((size_t)(b * 8 + h)) * 1048576 + (size_t)jd0 * 256;

    const int ln_ = lane & 15, quad = lane >> 4;
    const int m0 = (w >> 1) * 64, n0 = (w & 1) * 64;
    floatx4 acc[4][4] = {};

    for (int kt = 0; kt < 2; ++kt) {
        if (kt) __syncthreads();
        for (int it = 0; it < 16; ++it) {
            int cid = w * 1024 + it * 64 + lane;
            int isB = cid >> 11;
            int lc = cid & 2047;
            int r = lc >> 4;
            int ck = (lc & 15) ^ (r & 15);
            const short* g = (isB ? Bbase : Abase) + r * 256 + kt * 128 + ck * 8;
            __builtin_amdgcn_global_load_lds(AS1(g), AS3(&AB[cid * 8]), 16, 0, 0);
        }
        __syncthreads();

        for (int kk = 0; kk < 4; ++kk) {
            int ckb = kk * 4 + quad;
            short8 aq[4], bq[4];
#pragma unroll
            for (int t = 0; t < 4; ++t) {
                int r = m0 + t * 16 + ln_;
                aq[t] = *(const short8*)&AB[(r * 16 + (ckb ^ (r & 15))) * 8];
            }
#pragma unroll
            for (int t = 0; t < 4; ++t) {
                int r = n0 + t * 16 + ln_;
                bq[t] = *(const short8*)&AB[(2048 + r * 16 + (ckb ^ (r & 15))) * 8];
            }
#pragma unroll
            for (int mt = 0; mt < 4; ++mt)
#pragma unroll
                for (int nt = 0; nt < 4; ++nt)
                    acc[mt][nt] = __builtin_amdgcn_mfma_f32_16x16x32_bf16(aq[mt], bq[nt], acc[mt][nt], 0, 0, 0);
        }
    }

    const int ph = part * 8 + h;
#pragma unroll
    for (int mt = 0; mt < 4; ++mt) {
#pragma unroll
        for (int nt = 0; nt < 4; ++nt) {
            int j = (jd0 + n0 + nt * 16) >> 4;
#pragma unroll
            for (int r = 0; r < 4; ++r) {
                int i = i0 + m0 + mt * 16 + quad * 4 + r;
                size_t m = ((size_t)b * 256 + i) * 256 + j;
                VaP2[((size_t)ph * 131072 + m) * 16 + ln_] = f2bf(acc[mt][nt][r]);
            }
        }
    }
}

// ---------------------------------------------------------------------------
// K4: out[m][w] = sum_c A[m][c] * WOt[w][c] + bO[w]. A staged 32 KB/kt.
// ---------------------------------------------------------------------------
__global__ __launch_bounds__(256) void k4_proj(const short* __restrict__ VaP2,
                                               const short* __restrict__ WOt,
                                               const float* __restrict__ bO,
                                               float* __restrict__ out) {
    __shared__ short A_s[16384];  // 32 KB
    const int tid = threadIdx.x, lane = tid & 63, w = tid >> 6;
    const size_t m0g = (size_t)blockIdx.x * 128;
    const int ln_ = lane & 15, quad = lane >> 4;
    const int m0 = (w >> 1) * 64, n0 = (w & 1) * 64;
    floatx4 acc[4][4] = {};

    for (int kt = 0; kt < 2; ++kt) {
        if (kt) __syncthreads();
        for (int it = 0; it < 8; ++it) {
            int cid = w * 512 + it * 64 + lane;     // 0..2047
            int p = cid >> 8, rm = cid & 255, half = rm >> 7, m = rm & 127;
            const short* g = VaP2 + ((size_t)(kt * 8 + p) * 131072 + m0g + m) * 16 + half * 8;
            __builtin_amdgcn_global_load_lds(AS1(g), AS3(&A_s[cid * 8]), 16, 0, 0);
        }
        __syncthreads();

        for (int kk = 0; kk < 4; ++kk) {
            int ckb = kk * 4 + quad;
            int p = ckb >> 1, hf = ckb & 1;
            short8 aq[4], bq[4];
#pragma unroll
            for (int t = 0; t < 4; ++t) {
                int m = m0 + t * 16 + ln_;
                aq[t] = *(const short8*)&A_s[p * 2048 + hf * 1024 + m * 8];
            }
#pragma unroll
            for (int t = 0; t < 4; ++t) {
                int wr = n0 + t * 16 + ln_;
                bq[t] = *(const short8*)(WOt + wr * 256 + kt * 128 + ckb * 8);
            }
#pragma unroll
            for (int mt = 0; mt < 4; ++mt)
#pragma unroll
                for (int nt = 0; nt < 4; ++nt)
                    acc[mt][nt] = __builtin_amdgcn_mfma_f32_16x16x32_bf16(aq[mt], bq[nt], acc[mt][nt], 0, 0, 0);
        }
    }

#pragma unroll
    for (int nt = 0; nt < 4; ++nt) {
        int ww = n0 + nt * 16 + ln_;
        float bo = bO[ww];
#pragma unroll
        for (int mt = 0; mt < 4; ++mt) {
            size_t mb = m0g + m0 + mt * 16 + quad * 4;
#pragma unroll
            for (int r = 0; r < 4; ++r)
                out[(mb + r) * 128 + ww] = acc[mt][nt][r] + bo;
        }
    }
}

// ---------------------------------------------------------------------------
extern "C" void kernel_launch(void* const* d_in, const int* in_sizes, int n_in,
                              void* d_out, int out_size, void* d_ws, size_t ws_size,
                              hipStream_t stream) {
    (void)in_sizes; (void)n_in; (void)out_size; (void)ws_size;
    const float* e    = (const float*)d_in[0];
    const float* mask = (const float*)d_in[1];
    const float* ln_g = (const float*)d_in[2];
    const float* ln_b = (const float*)d_in[3];
    const float* W_V  = (const float*)d_in[4];
    const float* b_V  = (const float*)d_in[5];
    const float* W_E  = (const float*)d_in[6];
    const float* b_E  = (const float*)d_in[7];
    const float* W_O  = (const float*)d_in[8];
    const float* b_O  = (const float*)d_in[9];
    float* out = (float*)d_out;

    char* ws = (char*)d_ws;
    short* VinT  = (short*)(ws + 0);           //  33,554,432 B
    short* VoutT = (short*)(ws + 33554432);    //  33,554,432 B
    short* Ain   = (short*)(ws + 67108864);    //   2,097,152 B
    short* AoutT = (short*)(ws + 69206016);    //   2,097,152 B
    short* VaP2  = (short*)(ws + 71303168);    //  67,108,864 B
    short* Wcat2 = (short*)(ws + 138412032);   //      73,728 B
    short* WOt   = (short*)(ws + 138485760);   //      65,536 B
    float* bcat  = (float*)(ws + 138551296);   //       1,152 B

    k0_prep<<<417, 128, 0, stream>>>(W_V, W_E, W_O, Wcat2, WOt, b_V, b_E, bcat);
    k1_ln_proj<<<dim3(256, 2, 2), 256, 0, stream>>>(e, ln_g, ln_b, mask, Wcat2,
                                                    bcat, VinT, VoutT, Ain, AoutT);
    k3_einsum<<<dim3(2, 32, 32), 256, 0, stream>>>(Ain, AoutT, VinT, VoutT, VaP2);
    k4_proj<<<1024, 256, 0, stream>>>(VaP2, WOt, b_O, out);
}